// Round 4
// baseline (143.683 us; speedup 1.0000x reference)
//
#include <hip/hip_runtime.h>
#include <math.h>

#define TABN 2048
#define EPB_BLK 8        // LUT entries per block (4 waves, 2 entries/wave)
#define RPW 16           // rows per wave, deferred-reduce
#define D 1000
#define DV4 250          // 1000 floats = 250 float4; row stride 4000B is 16B-aligned

// ---------------- LUT kernel: tabulate f(s) = sigmoid(MLP(s)) over s in [-1,1] ----------
__global__ __launch_bounds__(256) void lut_kernel(
    const float* __restrict__ w1, const float* __restrict__ b1,
    const float* __restrict__ w2, const float* __restrict__ b2,
    const float* __restrict__ w3, const float* __restrict__ b3,
    const float* __restrict__ w4, const float* __restrict__ b4,
    float* __restrict__ lut)
{
    __shared__ float h1[EPB_BLK][512];
    __shared__ float h2s[EPB_BLK][64];
    const int tid  = threadIdx.x;
    const int lane = tid & 63;
    const int wid  = tid >> 6;               // 0..3
    const int e0 = blockIdx.x * EPB_BLK;

    // layer 1: 1 -> 512
    for (int j = tid; j < 512; j += 256) {
        float wj = w1[j], bj = b1[j];
#pragma unroll
        for (int e = 0; e < EPB_BLK; ++e) {
            float s = -1.0f + 2.0f * (float)(e0 + e) / (float)(TABN - 1);
            float v = fmaf(wj, s, bj);
            h1[e][j] = v > 0.0f ? v : 0.0f;
        }
    }
    __syncthreads();

    // layer 2: 512 -> 64. wave w owns entries 2w, 2w+1; lane = output unit k.
    const int ea = 2 * wid, eb = 2 * wid + 1;
    float acc0 = b2[lane], acc1 = acc0;
#pragma unroll 4
    for (int j = 0; j < 512; ++j) {
        float w = w2[j * 64 + lane];
        acc0 = fmaf(w, h1[ea][j], acc0);
        acc1 = fmaf(w, h1[eb][j], acc1);
    }
    h2s[ea][lane] = acc0 > 0.0f ? acc0 : 0.0f;
    h2s[eb][lane] = acc1 > 0.0f ? acc1 : 0.0f;
    // intra-wave LDS RAW only

    // layer 3 (64 -> 32) + layer 4 partial: lanes 0..31, m = lane
    float p0 = 0.0f, p1 = 0.0f;
    if (lane < 32) {
        float b3m = b3[lane];
        float w4m = w4[lane];
        float a0 = b3m, a1 = b3m;
#pragma unroll 4
        for (int k = 0; k < 64; ++k) {
            float wv = w3[k * 32 + lane];
            a0 = fmaf(wv, h2s[ea][k], a0);
            a1 = fmaf(wv, h2s[eb][k], a1);
        }
        p0 = (a0 > 0.0f ? a0 : 0.0f) * w4m;
        p1 = (a1 > 0.0f ? a1 : 0.0f) * w4m;
    }
#pragma unroll
    for (int off = 32; off >= 1; off >>= 1) {
        p0 += __shfl_down(p0, off, 64);
        p1 += __shfl_down(p1, off, 64);
    }
    if (lane == 0) {
        float b4v = b4[0];
        lut[e0 + ea] = 1.0f / (1.0f + expf(-(p0 + b4v)));
        lut[e0 + eb] = 1.0f / (1.0f + expf(-(p1 + b4v)));
    }
}

// ---------------- main kernel: R1 load pattern + deferred wave reduction ----------------
__device__ __forceinline__ float dot4(float4 a, float4 b, float acc) {
    acc = fmaf(a.x, b.x, acc);
    acc = fmaf(a.y, b.y, acc);
    acc = fmaf(a.z, b.z, acc);
    acc = fmaf(a.w, b.w, acc);
    return acc;
}

__global__ __launch_bounds__(256, 4) void sim_kernel(
    const float* __restrict__ query, const float* __restrict__ emb,
    const float* __restrict__ lut, float* __restrict__ out, int N)
{
    const int lane = threadIdx.x & 63;
    const int wave = blockIdx.x * 4 + (threadIdx.x >> 6);
    const size_t base0 = (size_t)wave * RPW;
    if (base0 >= (size_t)N) return;

    const float4 zero4 = make_float4(0.f, 0.f, 0.f, 0.f);
    const float4* q4 = (const float4*)query;
    float4 q0 = q4[lane];
    float4 q1 = q4[lane + 64];
    float4 q2 = q4[lane + 128];
    float4 q3 = (lane < DV4 - 192) ? q4[lane + 192] : zero4;

    // ||q||^2: full butterfly once per wave
    float nq = 0.f;
    nq = dot4(q0, q0, nq); nq = dot4(q1, q1, nq);
    nq = dot4(q2, q2, nq); nq = dot4(q3, q3, nq);
#pragma unroll
    for (int off = 32; off >= 1; off >>= 1) nq += __shfl_xor(nq, off, 64);
    const float qn = sqrtf(nq);

    // 16 rows: per-lane partials only; NO cross-lane ops inside the loop
    float dt[RPW], nn[RPW];
#pragma unroll
    for (int r = 0; r < RPW; ++r) {
        const float4* e4 = (const float4*)(emb + (base0 + (size_t)r) * D);
        float4 a0 = e4[lane];
        float4 a1 = e4[lane + 64];
        float4 a2 = e4[lane + 128];
        float4 a3 = (lane < DV4 - 192) ? e4[lane + 192] : zero4;
        float d = 0.f, n = 0.f;
        d = dot4(a0, q0, d); n = dot4(a0, a0, n);
        d = dot4(a1, q1, d); n = dot4(a1, a1, n);
        d = dot4(a2, q2, d); n = dot4(a2, a2, n);
        d = dot4(a3, q3, d); n = dot4(a3, a3, n);
        dt[r] = d; nn[r] = n;
    }

    // butterfly levels 1,2,4,8: 32 independent chains, interleaved (throughput-bound)
#pragma unroll
    for (int off = 1; off <= 8; off <<= 1) {
#pragma unroll
        for (int r = 0; r < RPW; ++r) {
            dt[r] += __shfl_xor(dt[r], off, 64);
            nn[r] += __shfl_xor(nn[r], off, 64);
        }
    }
    // static selection tree: lane l ends with row (l & 15)'s group-partial
    float da[8], na[8];
#pragma unroll
    for (int i = 0; i < 8; ++i) {
        da[i] = (lane & 1) ? dt[2*i+1] : dt[2*i];
        na[i] = (lane & 1) ? nn[2*i+1] : nn[2*i];
    }
    float db[4], nb[4];
#pragma unroll
    for (int i = 0; i < 4; ++i) {
        db[i] = (lane & 2) ? da[2*i+1] : da[2*i];
        nb[i] = (lane & 2) ? na[2*i+1] : na[2*i];
    }
    float dc[2], nc[2];
#pragma unroll
    for (int i = 0; i < 2; ++i) {
        dc[i] = (lane & 4) ? db[2*i+1] : db[2*i];
        nc[i] = (lane & 4) ? nb[2*i+1] : nb[2*i];
    }
    float dsel = (lane & 8) ? dc[1] : dc[0];
    float nsel = (lane & 8) ? nc[1] : nc[0];
    // final levels 16, 32 on the selected values only
    dsel += __shfl_xor(dsel, 16, 64);  nsel += __shfl_xor(nsel, 16, 64);
    dsel += __shfl_xor(dsel, 32, 64);  nsel += __shfl_xor(nsel, 32, 64);

    if (lane < 16) {
        float sim = dsel / fmaxf(sqrtf(nsel) * qn, 1e-8f);
        float t = (sim + 1.0f) * (0.5f * (float)(TABN - 1));
        t = fminf(fmaxf(t, 0.0f), (float)(TABN - 1));
        int i0 = (int)t;
        if (i0 > TABN - 2) i0 = TABN - 2;
        float fr = t - (float)i0;
        float v0 = lut[i0], v1 = lut[i0 + 1];
        out[base0 + lane] = fmaf(v1 - v0, fr, v0);   // 16 consecutive dwords
    }
}

extern "C" void kernel_launch(void* const* d_in, const int* in_sizes, int n_in,
                              void* d_out, int out_size, void* d_ws, size_t ws_size,
                              hipStream_t stream) {
    const float* query = (const float*)d_in[0];
    const float* emb   = (const float*)d_in[1];
    const float* w1    = (const float*)d_in[2];
    const float* b1    = (const float*)d_in[3];
    const float* w2    = (const float*)d_in[4];
    const float* b2    = (const float*)d_in[5];
    const float* w3    = (const float*)d_in[6];
    const float* b3    = (const float*)d_in[7];
    const float* w4    = (const float*)d_in[8];
    const float* b4    = (const float*)d_in[9];
    float* lut = (float*)d_ws;
    float* out = (float*)d_out;
    const int N = in_sizes[1] / D;   // 65536

    lut_kernel<<<TABN / EPB_BLK, 256, 0, stream>>>(w1, b1, w2, b2, w3, b3, w4, b4, lut);

    const int waves  = (N + RPW - 1) / RPW;      // 4096
    const int blocks = (waves + 3) / 4;          // 1024 = 4 blocks/CU exactly
    sim_kernel<<<blocks, 256, 0, stream>>>(query, emb, lut, out, N);
}

// Round 5
// 87.830 us; speedup vs baseline: 1.6359x; 1.6359x over previous
//
#include <hip/hip_runtime.h>
#include <math.h>

#define TABN 1024
#define EPB 4            // LUT entries per block (one wave per block)
#define RPW 8            // rows per wave
#define D 1000
#define DV4 250          // 1000 floats = 250 float4; row stride 4000B is 16B-aligned

// ---------------- LUT kernel (R1 known-good structure): f(s)=sigmoid(MLP(s)), s in [-1,1]
__global__ __launch_bounds__(64) void lut_kernel(
    const float* __restrict__ w1, const float* __restrict__ b1,
    const float* __restrict__ w2, const float* __restrict__ b2,
    const float* __restrict__ w3, const float* __restrict__ b3,
    const float* __restrict__ w4, const float* __restrict__ b4,
    float* __restrict__ lut)
{
    __shared__ float h1[EPB][512];
    __shared__ float h2s[EPB][64];
    const int lane = threadIdx.x;           // 64 threads = 1 wave
    const int e0 = blockIdx.x * EPB;

    float s[EPB];
#pragma unroll
    for (int e = 0; e < EPB; ++e)
        s[e] = -1.0f + 2.0f * (float)(e0 + e) / (float)(TABN - 1);

    for (int j = lane; j < 512; j += 64) {
        float wj = w1[j], bj = b1[j];
#pragma unroll
        for (int e = 0; e < EPB; ++e) {
            float v = fmaf(wj, s[e], bj);
            h1[e][j] = v > 0.0f ? v : 0.0f;
        }
    }
    __syncthreads();

    float acc[EPB];
    {
        float bk = b2[lane];
#pragma unroll
        for (int e = 0; e < EPB; ++e) acc[e] = bk;
    }
#pragma unroll 4
    for (int j = 0; j < 512; ++j) {
        float w = w2[j * 64 + lane];
#pragma unroll
        for (int e = 0; e < EPB; ++e)
            acc[e] = fmaf(w, h1[e][j], acc[e]);
    }
#pragma unroll
    for (int e = 0; e < EPB; ++e)
        h2s[e][lane] = acc[e] > 0.0f ? acc[e] : 0.0f;
    __syncthreads();

    float part[EPB];
#pragma unroll
    for (int e = 0; e < EPB; ++e) part[e] = 0.0f;
    if (lane < 32) {
        float b3m = b3[lane];
        float w4m = w4[lane];
#pragma unroll
        for (int e = 0; e < EPB; ++e) {
            float a = b3m;
            for (int k = 0; k < 64; ++k)
                a = fmaf(w3[k * 32 + lane], h2s[e][k], a);
            float h3 = a > 0.0f ? a : 0.0f;
            part[e] = h3 * w4m;
        }
    }
#pragma unroll
    for (int off = 32; off >= 1; off >>= 1) {
#pragma unroll
        for (int e = 0; e < EPB; ++e)
            part[e] += __shfl_down(part[e], off, 64);
    }
    if (lane == 0) {
        float b4v = b4[0];
#pragma unroll
        for (int e = 0; e < EPB; ++e) {
            float z = part[e] + b4v;
            lut[e0 + e] = 1.0f / (1.0f + expf(-z));
        }
    }
}

// ---------------- main kernel: R1 layout + issue-early pipeline + paired reduce --------
__device__ __forceinline__ float dot4(float4 a, float4 b, float acc) {
    acc = fmaf(a.x, b.x, acc);
    acc = fmaf(a.y, b.y, acc);
    acc = fmaf(a.z, b.z, acc);
    acc = fmaf(a.w, b.w, acc);
    return acc;
}

__global__ __launch_bounds__(256) void sim_kernel(
    const float* __restrict__ query, const float* __restrict__ emb,
    const float* __restrict__ lut, float* __restrict__ out, int N)
{
    const int lane = threadIdx.x & 63;
    const int wave = blockIdx.x * (blockDim.x >> 6) + (threadIdx.x >> 6);
    const size_t base0 = (size_t)wave * RPW;
    if (base0 >= (size_t)N) return;

    const float4 zero4 = make_float4(0.f, 0.f, 0.f, 0.f);
    const float4* q4 = (const float4*)query;
    float4 q0 = q4[lane];
    float4 q1 = q4[lane + 64];
    float4 q2 = q4[lane + 128];
    float4 q3 = (lane < DV4 - 192) ? q4[lane + 192] : zero4;

    float nq = 0.f;
    nq = dot4(q0, q0, nq); nq = dot4(q1, q1, nq);
    nq = dot4(q2, q2, nq); nq = dot4(q3, q3, nq);
#pragma unroll
    for (int off = 32; off >= 1; off >>= 1) nq += __shfl_xor(nq, off, 64);
    const float qn = sqrtf(nq);

    // --- helpers as macros so buffers stay statically named (no spills) ---
#define LOADROW(BUF, ROW)                                               \
    {                                                                   \
        const float4* e4 = (const float4*)(emb + (size_t)(ROW) * D);    \
        BUF[0] = e4[lane];                                              \
        BUF[1] = e4[lane + 64];                                         \
        BUF[2] = e4[lane + 128];                                        \
        BUF[3] = (lane < DV4 - 192) ? e4[lane + 192] : zero4;           \
    }

#define PROCROW(BUF, ROW)                                               \
    {                                                                   \
        float d = 0.f, n = 0.f;                                         \
        d = dot4(BUF[0], q0, d); n = dot4(BUF[0], BUF[0], n);           \
        d = dot4(BUF[1], q1, d); n = dot4(BUF[1], BUF[1], n);           \
        d = dot4(BUF[2], q2, d); n = dot4(BUF[2], BUF[2], n);           \
        d = dot4(BUF[3], q3, d); n = dot4(BUF[3], BUF[3], n);           \
        /* paired reduce: even lanes carry dot, odd carry nn */         \
        float td = __shfl_xor(d, 1, 64);                                \
        float tn = __shfl_xor(n, 1, 64);                                \
        float v = (lane & 1) ? (n + tn) : (d + td);                     \
        v += __shfl_xor(v, 2, 64);                                      \
        v += __shfl_xor(v, 4, 64);                                      \
        v += __shfl_xor(v, 8, 64);                                      \
        v += __shfl_xor(v, 16, 64);                                     \
        v += __shfl_xor(v, 32, 64);                                     \
        float o = __shfl_xor(v, 1, 64);                                 \
        if (lane == 0) {                                                \
            float sim = v / fmaxf(sqrtf(o) * qn, 1e-8f);                \
            float t = (sim + 1.0f) * (0.5f * (float)(TABN - 1));        \
            t = fminf(fmaxf(t, 0.0f), (float)(TABN - 1));               \
            int i0 = (int)t;                                            \
            if (i0 > TABN - 2) i0 = TABN - 2;                           \
            float fr = t - (float)i0;                                   \
            float v0 = lut[i0], v1 = lut[i0 + 1];                       \
            out[ROW] = fmaf(v1 - v0, fr, v0);                           \
        }                                                               \
    }

    float4 A[4], B[4];
    LOADROW(A, base0);
#pragma unroll 1
    for (int r = 0; r < RPW; r += 2) {
        LOADROW(B, base0 + r + 1);        // issue-early: in flight during A's reduce
        PROCROW(A, base0 + r);
        if (r + 2 < RPW) LOADROW(A, base0 + r + 2);
        PROCROW(B, base0 + r + 1);
    }
#undef LOADROW
#undef PROCROW
}

extern "C" void kernel_launch(void* const* d_in, const int* in_sizes, int n_in,
                              void* d_out, int out_size, void* d_ws, size_t ws_size,
                              hipStream_t stream) {
    const float* query = (const float*)d_in[0];
    const float* emb   = (const float*)d_in[1];
    const float* w1    = (const float*)d_in[2];
    const float* b1    = (const float*)d_in[3];
    const float* w2    = (const float*)d_in[4];
    const float* b2    = (const float*)d_in[5];
    const float* w3    = (const float*)d_in[6];
    const float* b3    = (const float*)d_in[7];
    const float* w4    = (const float*)d_in[8];
    const float* b4    = (const float*)d_in[9];
    float* lut = (float*)d_ws;
    float* out = (float*)d_out;
    const int N = in_sizes[1] / D;   // 65536

    lut_kernel<<<TABN / EPB, 64, 0, stream>>>(w1, b1, w2, b2, w3, b3, w4, b4, lut);

    const int waves  = (N + RPW - 1) / RPW;      // 8192
    const int blocks = (waves + 3) / 4;          // 2048
    sim_kernel<<<blocks, 256, 0, stream>>>(query, emb, lut, out, N);
}

// Round 6
// 62.061 us; speedup vs baseline: 2.3152x; 1.4152x over previous
//
#include <hip/hip_runtime.h>
#include <math.h>

#define TABN 512
#define LE 4             // LUT entries per block
#define ROWS_PER_WAVE 8
#define D 1000
#define DV4 250          // 1000 floats = 250 float4; row stride 4000B is 16B-aligned

// ---------------- LUT kernel: wide layout, 128 blocks x 256 threads ----------------
// f(s) = sigmoid(MLP(s)) tabulated over s in [-1,1].
__global__ __launch_bounds__(256) void lut_kernel(
    const float* __restrict__ w1, const float* __restrict__ b1,
    const float* __restrict__ w2, const float* __restrict__ b2,
    const float* __restrict__ w3, const float* __restrict__ b3,
    const float* __restrict__ w4, const float* __restrict__ b4,
    float* __restrict__ lut)
{
    __shared__ float h1s[LE][512];      // 8 KB
    __shared__ float pl2[LE][4][64];    // 4 KB
    __shared__ float h2s[LE][64];       // 1 KB
    const int t  = threadIdx.x;
    const int k  = t & 63;              // layer-2 output unit
    const int jc = t >> 6;              // j-chunk 0..3 (one per wave)
    const int e0 = blockIdx.x * LE;

    float s[LE];
#pragma unroll
    for (int e = 0; e < LE; ++e)
        s[e] = -1.0f + 2.0f * (float)(e0 + e) / (float)(TABN - 1);

    // layer 1: 1 -> 512
#pragma unroll
    for (int j = t; j < 512; j += 256) {
        float wj = w1[j], bj = b1[j];
#pragma unroll
        for (int e = 0; e < LE; ++e) {
            float v = fmaf(wj, s[e], bj);
            h1s[e][j] = v > 0.0f ? v : 0.0f;
        }
    }
    __syncthreads();

    // layer 2: 512 -> 64, j split 4 ways. Per wave all lanes share jc:
    // w2 load coalesced over k; h1s read is same-address broadcast.
    float pacc[LE] = {0.f, 0.f, 0.f, 0.f};
    const int jbase = jc * 128;
#pragma unroll 4
    for (int jj = 0; jj < 128; ++jj) {
        int j = jbase + jj;
        float w = w2[j * 64 + k];
#pragma unroll
        for (int e = 0; e < LE; ++e)
            pacc[e] = fmaf(w, h1s[e][j], pacc[e]);
    }
#pragma unroll
    for (int e = 0; e < LE; ++e) pl2[e][jc][k] = pacc[e];
    __syncthreads();

    // combine partials + relu (wave 0 only)
    if (t < 64) {
#pragma unroll
        for (int e = 0; e < LE; ++e) {
            float a = b2[k] + ((pl2[e][0][k] + pl2[e][1][k]) +
                               (pl2[e][2][k] + pl2[e][3][k]));
            h2s[e][k] = a > 0.0f ? a : 0.0f;
        }
    }
    __syncthreads();

    // layer 3 (64->32) + layer 4 (32->1): threads 0..127, e = t>>5, m = t&31
    if (t < 32 * LE) {
        const int e = t >> 5, m = t & 31;
        float a = b3[m];
#pragma unroll 4
        for (int kk = 0; kk < 64; ++kk)
            a = fmaf(w3[kk * 32 + m], h2s[e][kk], a);
        float h3 = a > 0.0f ? a : 0.0f;
        float part = h3 * w4[m];
#pragma unroll
        for (int off = 16; off >= 1; off >>= 1)
            part += __shfl_xor(part, off, 32);
        if (m == 0)
            lut[e0 + e] = 1.0f / (1.0f + expf(-(part + b4[0])));
    }
}

// ---------------- main kernel: byte-identical to R1 (proven 74.8 us) ----------------
__device__ __forceinline__ float dot4(float4 a, float4 b, float acc) {
    acc = fmaf(a.x, b.x, acc);
    acc = fmaf(a.y, b.y, acc);
    acc = fmaf(a.z, b.z, acc);
    acc = fmaf(a.w, b.w, acc);
    return acc;
}

__global__ __launch_bounds__(256) void sim_kernel(
    const float* __restrict__ query, const float* __restrict__ emb,
    const float* __restrict__ lut, float* __restrict__ out, int N)
{
    const int lane = threadIdx.x & 63;
    const int wave = blockIdx.x * (blockDim.x >> 6) + (threadIdx.x >> 6);

    const float4 zero4 = make_float4(0.f, 0.f, 0.f, 0.f);
    const float4* q4 = (const float4*)query;
    float4 q0 = q4[lane];
    float4 q1 = q4[lane + 64];
    float4 q2 = q4[lane + 128];
    float4 q3 = (lane < DV4 - 192) ? q4[lane + 192] : zero4;

    float nq = 0.f;
    nq = dot4(q0, q0, nq); nq = dot4(q1, q1, nq);
    nq = dot4(q2, q2, nq); nq = dot4(q3, q3, nq);
#pragma unroll
    for (int off = 32; off >= 1; off >>= 1) nq += __shfl_xor(nq, off, 64);
    const float qn = sqrtf(nq);

#pragma unroll 1
    for (int r = 0; r < ROWS_PER_WAVE; ++r) {
        const int row = wave * ROWS_PER_WAVE + r;
        if (row >= N) break;
        const float4* e4 = (const float4*)(emb + (size_t)row * D);
        float4 a0 = e4[lane];
        float4 a1 = e4[lane + 64];
        float4 a2 = e4[lane + 128];
        float4 a3 = (lane < DV4 - 192) ? e4[lane + 192] : zero4;

        float dot = 0.f, nn = 0.f;
        dot = dot4(a0, q0, dot); nn = dot4(a0, a0, nn);
        dot = dot4(a1, q1, dot); nn = dot4(a1, a1, nn);
        dot = dot4(a2, q2, dot); nn = dot4(a2, a2, nn);
        dot = dot4(a3, q3, dot); nn = dot4(a3, a3, nn);
#pragma unroll
        for (int off = 32; off >= 1; off >>= 1) {
            dot += __shfl_xor(dot, off, 64);
            nn  += __shfl_xor(nn,  off, 64);
        }
        if (lane == 0) {
            float sim = dot / fmaxf(sqrtf(nn) * qn, 1e-8f);
            float t = (sim + 1.0f) * (0.5f * (float)(TABN - 1));
            t = fminf(fmaxf(t, 0.0f), (float)(TABN - 1));
            int i0 = (int)t;
            if (i0 > TABN - 2) i0 = TABN - 2;
            float fr = t - (float)i0;
            float v0 = lut[i0], v1 = lut[i0 + 1];
            out[row] = fmaf(v1 - v0, fr, v0);
        }
    }
}

extern "C" void kernel_launch(void* const* d_in, const int* in_sizes, int n_in,
                              void* d_out, int out_size, void* d_ws, size_t ws_size,
                              hipStream_t stream) {
    const float* query = (const float*)d_in[0];
    const float* emb   = (const float*)d_in[1];
    const float* w1    = (const float*)d_in[2];
    const float* b1    = (const float*)d_in[3];
    const float* w2    = (const float*)d_in[4];
    const float* b2    = (const float*)d_in[5];
    const float* w3    = (const float*)d_in[6];
    const float* b3    = (const float*)d_in[7];
    const float* w4    = (const float*)d_in[8];
    const float* b4    = (const float*)d_in[9];
    float* lut = (float*)d_ws;
    float* out = (float*)d_out;
    const int N = in_sizes[1] / D;   // 65536

    lut_kernel<<<TABN / LE, 256, 0, stream>>>(w1, b1, w2, b2, w3, b3, w4, b4, lut);

    const int waves = (N + ROWS_PER_WAVE - 1) / ROWS_PER_WAVE;
    const int blocks = (waves + 3) / 4;      // 4 waves (256 threads) per block
    sim_kernel<<<blocks, 256, 0, stream>>>(query, emb, lut, out, N);
}

// Round 7
// 60.605 us; speedup vs baseline: 2.3708x; 1.0240x over previous
//
#include <hip/hip_runtime.h>
#include <math.h>

#define TABN 512
#define LE 4             // LUT entries per block
#define RPW 8            // rows per wave
#define D 1000
#define DV4 250          // 1000 floats = 250 float4; row stride 4000B is 16B-aligned

// ---------------- LUT kernel: wide layout, 128 blocks x 256 threads (R6, proven) -------
__global__ __launch_bounds__(256) void lut_kernel(
    const float* __restrict__ w1, const float* __restrict__ b1,
    const float* __restrict__ w2, const float* __restrict__ b2,
    const float* __restrict__ w3, const float* __restrict__ b3,
    const float* __restrict__ w4, const float* __restrict__ b4,
    float* __restrict__ lut)
{
    __shared__ float h1s[LE][512];      // 8 KB
    __shared__ float pl2[LE][4][64];    // 4 KB
    __shared__ float h2s[LE][64];       // 1 KB
    const int t  = threadIdx.x;
    const int k  = t & 63;              // layer-2 output unit
    const int jc = t >> 6;              // j-chunk 0..3 (one per wave)
    const int e0 = blockIdx.x * LE;

    float s[LE];
#pragma unroll
    for (int e = 0; e < LE; ++e)
        s[e] = -1.0f + 2.0f * (float)(e0 + e) / (float)(TABN - 1);

    // layer 1: 1 -> 512
#pragma unroll
    for (int j = t; j < 512; j += 256) {
        float wj = w1[j], bj = b1[j];
#pragma unroll
        for (int e = 0; e < LE; ++e) {
            float v = fmaf(wj, s[e], bj);
            h1s[e][j] = v > 0.0f ? v : 0.0f;
        }
    }
    __syncthreads();

    // layer 2: 512 -> 64, j split 4 ways across waves
    float pacc[LE] = {0.f, 0.f, 0.f, 0.f};
    const int jbase = jc * 128;
#pragma unroll 4
    for (int jj = 0; jj < 128; ++jj) {
        int j = jbase + jj;
        float w = w2[j * 64 + k];
#pragma unroll
        for (int e = 0; e < LE; ++e)
            pacc[e] = fmaf(w, h1s[e][j], pacc[e]);
    }
#pragma unroll
    for (int e = 0; e < LE; ++e) pl2[e][jc][k] = pacc[e];
    __syncthreads();

    if (t < 64) {
#pragma unroll
        for (int e = 0; e < LE; ++e) {
            float a = b2[k] + ((pl2[e][0][k] + pl2[e][1][k]) +
                               (pl2[e][2][k] + pl2[e][3][k]));
            h2s[e][k] = a > 0.0f ? a : 0.0f;
        }
    }
    __syncthreads();

    // layer 3 (64->32) + layer 4 (32->1): threads 0..127, e = t>>5, m = t&31
    if (t < 32 * LE) {
        const int e = t >> 5, m = t & 31;
        float a = b3[m];
#pragma unroll 4
        for (int kk = 0; kk < 64; ++kk)
            a = fmaf(w3[kk * 32 + m], h2s[e][kk], a);
        float h3 = a > 0.0f ? a : 0.0f;
        float part = h3 * w4[m];
#pragma unroll
        for (int off = 16; off >= 1; off >>= 1)
            part += __shfl_xor(part, off, 32);
        if (m == 0)
            lut[e0 + e] = 1.0f / (1.0f + expf(-(part + b4[0])));
    }
}

// ---------------- main kernel: R6 math + LDS-lut + depth-1 load pipeline ----------------
__device__ __forceinline__ float dot4(float4 a, float4 b, float acc) {
    acc = fmaf(a.x, b.x, acc);
    acc = fmaf(a.y, b.y, acc);
    acc = fmaf(a.z, b.z, acc);
    acc = fmaf(a.w, b.w, acc);
    return acc;
}

__global__ __launch_bounds__(256) void sim_kernel(
    const float* __restrict__ query, const float* __restrict__ emb,
    const float* __restrict__ lut, float* __restrict__ out, int N)
{
    __shared__ float sLut[TABN];        // 2 KB: lut gathers become LDS reads (lgkmcnt),
    const int t = threadIdx.x;          // so prefetched global loads stay in flight
    for (int i = t; i < TABN; i += 256) sLut[i] = lut[i];
    __syncthreads();

    const int lane = t & 63;
    const int wave = blockIdx.x * 4 + (t >> 6);
    const size_t base0 = (size_t)wave * RPW;
    if (base0 >= (size_t)N) return;

    const float4 zero4 = make_float4(0.f, 0.f, 0.f, 0.f);
    const float4* q4 = (const float4*)query;
    float4 q0 = q4[lane];
    float4 q1 = q4[lane + 64];
    float4 q2 = q4[lane + 128];
    float4 q3 = (lane < DV4 - 192) ? q4[lane + 192] : zero4;

    float nq = 0.f;
    nq = dot4(q0, q0, nq); nq = dot4(q1, q1, nq);
    nq = dot4(q2, q2, nq); nq = dot4(q3, q3, nq);
#pragma unroll
    for (int off = 32; off >= 1; off >>= 1) nq += __shfl_xor(nq, off, 64);
    const float qn = sqrtf(nq);

    // named buffers (never arrays -> never scratch)
    float4 A0, A1, A2, A3, B0, B1, B2, B3;

#define LOADROW(P0, P1, P2, P3, ROW)                                    \
    {                                                                   \
        const float4* e4 = (const float4*)(emb + (size_t)(ROW) * D);    \
        P0 = e4[lane];                                                  \
        P1 = e4[lane + 64];                                             \
        P2 = e4[lane + 128];                                            \
        P3 = (lane < DV4 - 192) ? e4[lane + 192] : zero4;               \
    }

#define PROCROW(P0, P1, P2, P3, ROW)                                    \
    {                                                                   \
        float dt = 0.f, nn = 0.f;                                       \
        dt = dot4(P0, q0, dt); nn = dot4(P0, P0, nn);                   \
        dt = dot4(P1, q1, dt); nn = dot4(P1, P1, nn);                   \
        dt = dot4(P2, q2, dt); nn = dot4(P2, P2, nn);                   \
        dt = dot4(P3, q3, dt); nn = dot4(P3, P3, nn);                   \
        _Pragma("unroll")                                               \
        for (int off = 32; off >= 1; off >>= 1) {                       \
            dt += __shfl_xor(dt, off, 64);                              \
            nn += __shfl_xor(nn, off, 64);                              \
        }                                                               \
        /* butterfly broadcasts: all lanes compute (uniform) */         \
        float sim = dt / fmaxf(sqrtf(nn) * qn, 1e-8f);                  \
        float tt = (sim + 1.0f) * (0.5f * (float)(TABN - 1));           \
        tt = fminf(fmaxf(tt, 0.0f), (float)(TABN - 1));                 \
        int i0 = (int)tt;                                               \
        if (i0 > TABN - 2) i0 = TABN - 2;                               \
        float fr = tt - (float)i0;                                      \
        float v0 = sLut[i0], v1 = sLut[i0 + 1];                         \
        if (lane == 0) out[ROW] = fmaf(v1 - v0, fr, v0);                \
    }

    LOADROW(A0, A1, A2, A3, base0);
#pragma unroll 1
    for (int r = 0; r < RPW; r += 2) {
        LOADROW(B0, B1, B2, B3, base0 + r + 1);   // in flight during A's reduce
        PROCROW(A0, A1, A2, A3, base0 + r);
        if (r + 2 < RPW) LOADROW(A0, A1, A2, A3, base0 + r + 2);
        PROCROW(B0, B1, B2, B3, base0 + r + 1);
    }
#undef LOADROW
#undef PROCROW
}

extern "C" void kernel_launch(void* const* d_in, const int* in_sizes, int n_in,
                              void* d_out, int out_size, void* d_ws, size_t ws_size,
                              hipStream_t stream) {
    const float* query = (const float*)d_in[0];
    const float* emb   = (const float*)d_in[1];
    const float* w1    = (const float*)d_in[2];
    const float* b1    = (const float*)d_in[3];
    const float* w2    = (const float*)d_in[4];
    const float* b2    = (const float*)d_in[5];
    const float* w3    = (const float*)d_in[6];
    const float* b3    = (const float*)d_in[7];
    const float* w4    = (const float*)d_in[8];
    const float* b4    = (const float*)d_in[9];
    float* lut = (float*)d_ws;
    float* out = (float*)d_out;
    const int N = in_sizes[1] / D;   // 65536

    lut_kernel<<<TABN / LE, 256, 0, stream>>>(w1, b1, w2, b2, w3, b3, w4, b4, lut);

    const int waves  = (N + RPW - 1) / RPW;      // 8192
    const int blocks = (waves + 3) / 4;          // 2048
    sim_kernel<<<blocks, 256, 0, stream>>>(query, emb, lut, out, N);
}